// Round 6
// baseline (2661.437 us; speedup 1.0000x reference)
//
#include <hip/hip_runtime.h>
#include <cstddef>

#define TPB 256

typedef _Float16 f16;
typedef _Float16 f16x4 __attribute__((ext_vector_type(4)));
typedef _Float16 f16x8 __attribute__((ext_vector_type(8)));
typedef float f32x4 __attribute__((ext_vector_type(4)));
typedef unsigned long long u64;

// ---------------------------------------------------------------------------
// block reduction (for chanconv)
// ---------------------------------------------------------------------------
__device__ __forceinline__ float block_sum(float v, float* red) {
  int tid = threadIdx.x;
  red[tid] = v; __syncthreads();
#pragma unroll
  for (int off = 128; off > 0; off >>= 1) {
    if (tid < off) red[tid] += red[tid + off];
    __syncthreads();
  }
  float r = red[0];
  __syncthreads();
  return r;
}

// ---------------------------------------------------------------------------
// h0 build: h0[im][4][1024]
// ---------------------------------------------------------------------------
__global__ __launch_bounds__(TPB) void build_h0(const float* __restrict__ kp0,
                                                const float* __restrict__ kp1,
                                                const float* __restrict__ sc0,
                                                const float* __restrict__ sc1,
                                                float* __restrict__ h0) {
  int n = blockIdx.x * TPB + threadIdx.x;
  int im = blockIdx.y;
  const float* kp = im ? kp1 : kp0;
  const float* sc = im ? sc1 : sc0;
  float* h = h0 + (size_t)im * 4096;
  h[n]        = kp[n * 3 + 0];
  h[1024 + n] = kp[n * 3 + 1];
  h[2048 + n] = kp[n * 3 + 2];
  h[3072 + n] = sc[n];
}

// ---------------------------------------------------------------------------
// kenc conv layer (fp32, small)
// ---------------------------------------------------------------------------
template<bool NORMRELU, bool RESID>
__global__ __launch_bounds__(TPB) void chanconv(const float* __restrict__ W,
                                                const float* __restrict__ bias,
                                                const float* __restrict__ in, long instride,
                                                const float* res0, const float* res1,
                                                float* __restrict__ out, long outstride, int C) {
  int o = blockIdx.x, im = blockIdx.y, tid = threadIdx.x;
  const float* inp = in + (long)im * instride;
  __shared__ float Ws[128];
  __shared__ float red[TPB];
  for (int c = tid; c < C; c += TPB) Ws[c] = W[(long)o * C + c];
  __syncthreads();
  float b = bias[o];
  float4 acc = {b, b, b, b};
  for (int c = 0; c < C; ++c) {
    float w = Ws[c];
    float4 v = *(const float4*)(inp + (long)c * 1024 + tid * 4);
    acc.x += w * v.x; acc.y += w * v.y; acc.z += w * v.z; acc.w += w * v.w;
  }
  float* orow = out + (long)im * outstride + (long)o * 1024;
  if (NORMRELU) {
    float s = acc.x + acc.y + acc.z + acc.w;
    float mean = block_sum(s, red) * (1.f / 1024.f);
    float dx = acc.x - mean, dy = acc.y - mean, dz = acc.z - mean, dw = acc.w - mean;
    float var = block_sum(dx * dx + dy * dy + dz * dz + dw * dw, red) * (1.f / 1024.f);
    float rstd = rsqrtf(var + 1e-5f);
    float4 o4 = {fmaxf(dx * rstd, 0.f), fmaxf(dy * rstd, 0.f),
                 fmaxf(dz * rstd, 0.f), fmaxf(dw * rstd, 0.f)};
    *(float4*)(orow + tid * 4) = o4;
  } else {
    if (RESID) {
      const float* res = im ? res1 : res0;
      float4 r = *(const float4*)(res + (long)o * 1024 + tid * 4);
      acc.x += r.x; acc.y += r.y; acc.z += r.z; acc.w += r.w;
    }
    *(float4*)(orow + tid * 4) = acc;
  }
}

// ---------------------------------------------------------------------------
// fp16-MFMA batched GEMM. Block 64xBN, 4 waves (2x2), wave 32x(BN/2).
// MFMA v_mfma_f32_16x16x16_f16; A-frag lane l: row=l&15, k=4*(l>>4)+j;
// B-frag: col=l&15, same k; D: col=l&15, row=4*(l>>4)+reg.
// LDS: As[m][k] / Bs[n][k] with k-contiguous rows, pitch 36 f16.
//   ASRC 0: fp32 [m][k]   1: f16 [k][m]   2: f16 [m][k] + softmax exp (mu=M, rs=inv)
//   BSRC 0: fp32 [k][n] (+concat B2)   1: f16 [k][n] (+inorm-relu)   2: f16 [n][k] (+add B2)
// FLAGS: 1 BNORM, 2 BCONCAT, 4 BADD, 8 CD16-out, 16 RES(fp32), 32 OUT2(sink triple), 64 CSCAT
// ---------------------------------------------------------------------------
struct GBH {
  const void* A; const void* B; const void* B2; void* C;
  const float* bias; const float* res; const float* mu; const float* rs;
  void* o2a; void* o2b; int coff; int pad;
};
struct GB16 { GBH g[16]; };

#define F_BNORM   1
#define F_BCONCAT 2
#define F_BADD    4
#define F_CD16    8
#define F_RES     16
#define F_OUT2    32
#define F_CSCAT   64

template<int BN, int ASRC, int BSRC, int FLAGS>
__global__ __launch_bounds__(TPB) void gemmh(GB16 gbs, int K, int lda, int ldb,
                                             int ldc, float alpha, int ksplit) {
  constexpr int WN = BN / 2;
  constexpr int NFR = WN / 16;
  GBH g = gbs.g[blockIdx.z];
  const int tid = threadIdx.x;
  const int lane = tid & 63, wid = tid >> 6;
  const int wm = wid >> 1, wn = wid & 1;
  const int m0 = blockIdx.y * 64, n0 = blockIdx.x * BN;
  __shared__ f16 As[64][36];
  __shared__ f16 Bs[BN][36];
  f32x4 acc[2][NFR];
#pragma unroll
  for (int i = 0; i < 2; ++i)
#pragma unroll
    for (int j = 0; j < NFR; ++j) acc[i][j] = (f32x4){0.f, 0.f, 0.f, 0.f};

  for (int k0 = 0; k0 < K; k0 += 32) {
    // ---- stage A ----
    if constexpr (ASRC == 0) {
      const int m = tid >> 2, k4 = (tid & 3) * 8;
      const float* ap = (const float*)g.A + (long)(m0 + m) * lda + k0 + k4;
      float4 u0 = *(const float4*)ap, u1 = *(const float4*)(ap + 4);
      f16x4 h0 = {(f16)u0.x, (f16)u0.y, (f16)u0.z, (f16)u0.w};
      f16x4 h1 = {(f16)u1.x, (f16)u1.y, (f16)u1.z, (f16)u1.w};
      *(f16x4*)&As[m][k4] = h0;
      *(f16x4*)&As[m][k4 + 4] = h1;
    } else if constexpr (ASRC == 1) {
      const int k = tid >> 3, mg = (tid & 7) * 8;
      const f16* ap = (const f16*)g.A + (long)(k0 + k) * lda + m0 + mg;
      f16x8 h = *(const f16x8*)ap;
#pragma unroll
      for (int j = 0; j < 8; ++j) As[mg + j][k] = h[j];
    } else {
      const int m = tid >> 2, k4 = (tid & 3) * 8;
      const f16* ap = (const f16*)g.A + (long)(m0 + m) * lda + k0 + k4;
      f16x8 h = *(const f16x8*)ap;
      const float M = g.mu[m0 + m], Iv = g.rs[m0 + m];
      f16x4 h0, h1;
#pragma unroll
      for (int j = 0; j < 4; ++j) h0[j] = (f16)(__expf((float)h[j] - M) * Iv);
#pragma unroll
      for (int j = 0; j < 4; ++j) h1[j] = (f16)(__expf((float)h[j + 4] - M) * Iv);
      *(f16x4*)&As[m][k4] = h0;
      *(f16x4*)&As[m][k4 + 4] = h1;
    }
    // ---- stage B ----
#pragma unroll
    for (int r = 0; r < BN / 64; ++r) {
      if constexpr (BSRC == 0) {
        const int k = tid >> 3, ng = (tid & 7) * 8 + r * 64;
        const int kg = k0 + k;
        const float* bp;
        if constexpr ((FLAGS & F_BCONCAT) != 0)
          bp = (kg < ksplit) ? ((const float*)g.B + (long)kg * ldb)
                             : ((const float*)g.B2 + (long)(kg - ksplit) * ldb);
        else
          bp = (const float*)g.B + (long)kg * ldb;
        float4 u0 = *(const float4*)(bp + n0 + ng);
        float4 u1 = *(const float4*)(bp + n0 + ng + 4);
        Bs[ng + 0][k] = (f16)u0.x; Bs[ng + 1][k] = (f16)u0.y;
        Bs[ng + 2][k] = (f16)u0.z; Bs[ng + 3][k] = (f16)u0.w;
        Bs[ng + 4][k] = (f16)u1.x; Bs[ng + 5][k] = (f16)u1.y;
        Bs[ng + 6][k] = (f16)u1.z; Bs[ng + 7][k] = (f16)u1.w;
      } else if constexpr (BSRC == 1) {
        const int k = tid >> 3, ng = (tid & 7) * 8 + r * 64;
        const int kg = k0 + k;
        f16x8 h = *(const f16x8*)((const f16*)g.B + (long)kg * ldb + n0 + ng);
        if constexpr ((FLAGS & F_BNORM) != 0) {
          const float mu = g.mu[kg], rs = g.rs[kg];
#pragma unroll
          for (int j = 0; j < 8; ++j)
            h[j] = (f16)fmaxf(((float)h[j] - mu) * rs, 0.f);
        }
#pragma unroll
        for (int j = 0; j < 8; ++j) Bs[ng + j][k] = h[j];
      } else {
        const int n = (tid >> 2) + r * 64, k4 = (tid & 3) * 8;
        const f16* bp = (const f16*)g.B + (long)(n0 + n) * ldb + k0 + k4;
        f16x8 h = *(const f16x8*)bp;
        if constexpr ((FLAGS & F_BADD) != 0) {
          f16x8 h2 = *(const f16x8*)((const f16*)g.B2 + (long)(n0 + n) * ldb + k0 + k4);
          h = h + h2;
        }
        f16x4 h0 = {h[0], h[1], h[2], h[3]};
        f16x4 h1 = {h[4], h[5], h[6], h[7]};
        *(f16x4*)&Bs[n][k4] = h0;
        *(f16x4*)&Bs[n][k4 + 4] = h1;
      }
    }
    __syncthreads();
    // ---- MFMA ----
#pragma unroll
    for (int ks = 0; ks < 2; ++ks) {
      const int kof = ks * 16 + ((lane >> 4) << 2);
      f16x4 a[2], b[NFR];
      a[0] = *(const f16x4*)&As[wm * 32 + (lane & 15)][kof];
      a[1] = *(const f16x4*)&As[wm * 32 + 16 + (lane & 15)][kof];
#pragma unroll
      for (int fn = 0; fn < NFR; ++fn)
        b[fn] = *(const f16x4*)&Bs[wn * WN + fn * 16 + (lane & 15)][kof];
#pragma unroll
      for (int fm = 0; fm < 2; ++fm)
#pragma unroll
        for (int fn = 0; fn < NFR; ++fn)
          acc[fm][fn] = __builtin_amdgcn_mfma_f32_16x16x16f16(a[fm], b[fn], acc[fm][fn], 0, 0, 0);
    }
    __syncthreads();
  }

  // ---- epilogue ----
  const int r0 = (lane >> 4) << 2, cn = lane & 15;
#pragma unroll
  for (int fm = 0; fm < 2; ++fm) {
#pragma unroll
    for (int r = 0; r < 4; ++r) {
      const int m = m0 + wm * 32 + fm * 16 + r0 + r;
      const float bi = g.bias ? g.bias[m] : 0.f;
#pragma unroll
      for (int fn = 0; fn < NFR; ++fn) {
        const int n = n0 + wn * WN + fn * 16 + cn;
        float v = acc[fm][fn][r] * alpha + bi;
        if constexpr ((FLAGS & F_RES) != 0) v += g.res[(long)m * ldc + n];
        if constexpr ((FLAGS & F_OUT2) != 0) {
          ((float*)g.C)[(long)m * 1028 + n] = v;
          ((f16*)g.o2a)[(long)m * 1028 + n] = (f16)v;
          ((f16*)g.o2b)[(long)n * 1028 + m] = (f16)v;
        } else if constexpr ((FLAGS & F_CSCAT) != 0) {
          ((f16*)g.C)[(long)m * ldc + g.coff + 4 * n] = (f16)v;
        } else if constexpr ((FLAGS & F_CD16) != 0) {
          ((f16*)g.C)[(long)m * ldc + n] = (f16)v;
        } else {
          ((float*)g.C)[(long)m * ldc + n] = v;
        }
      }
    }
  }
}

// ---------------------------------------------------------------------------
// rowlse over f16 S rows (1024 wide): Mrow, Inv = 1/sum(exp(x-M)). Wave/row.
// ---------------------------------------------------------------------------
__global__ __launch_bounds__(TPB) void rowlse_h(const f16* __restrict__ S,
                                                float* __restrict__ Mrow,
                                                float* __restrict__ Inv) {
  int row = blockIdx.x * 4 + (threadIdx.x >> 6);
  int lane = threadIdx.x & 63;
  const f16x8* p = (const f16x8*)(S + (long)row * 1024);
  f16x8 v0 = p[lane], v1 = p[lane + 64];
  float m = -1e30f;
#pragma unroll
  for (int j = 0; j < 8; ++j)
    m = fmaxf(m, fmaxf((float)v0[j], (float)v1[j]));
#pragma unroll
  for (int off = 32; off > 0; off >>= 1) m = fmaxf(m, __shfl_xor(m, off));
  float s = 0.f;
#pragma unroll
  for (int j = 0; j < 8; ++j)
    s += __expf((float)v0[j] - m) + __expf((float)v1[j] - m);
#pragma unroll
  for (int off = 32; off > 0; off >>= 1) s += __shfl_xor(s, off);
  if (lane == 0) { Mrow[row] = m; Inv[row] = 1.f / s; }
}

// ---------------------------------------------------------------------------
// rowstats over f16 tb rows (1024 wide): mean, rsqrt(var+eps). Wave/row.
// ---------------------------------------------------------------------------
__global__ __launch_bounds__(TPB) void rowstats2_h(const f16* __restrict__ t,
                                                   float* __restrict__ mu,
                                                   float* __restrict__ rs) {
  int row = blockIdx.x * 4 + (threadIdx.x >> 6);
  int lane = threadIdx.x & 63;
  const f16x8* p = (const f16x8*)(t + (long)row * 1024);
  f16x8 v0 = p[lane], v1 = p[lane + 64];
  float s = 0.f, s2 = 0.f;
#pragma unroll
  for (int j = 0; j < 8; ++j) {
    float a = (float)v0[j], b = (float)v1[j];
    s += a + b; s2 += a * a + b * b;
  }
#pragma unroll
  for (int off = 32; off > 0; off >>= 1) { s += __shfl_xor(s, off); s2 += __shfl_xor(s2, off); }
  if (lane == 0) {
    float mean = s * (1.f / 1024.f);
    mu[row] = mean;
    rs[row] = rsqrtf(fmaxf(s2 * (1.f / 1024.f) - mean * mean, 0.f) + 1e-5f);
  }
}

// ---------------------------------------------------------------------------
// Sinkhorn — persistent, Z in registers, BARRIER-FREE dataflow sync:
// u/v live as 1025 x 8-byte slots (hi32 = generation, lo32 = fp32 value),
// accessed only with relaxed agent-scope 8B atomics (bypass non-coherent
// per-XCD L2s; single 8B store is indivisible so value+gen arrive together).
// A wave polls all input slots for tag==gen (17 loads in flight), computes,
// stores its rows tagged gen+1. Every wave reads the FULL input vector before
// storing any output, so gen g+2 never overwrites a slot still needed at g.
// ---------------------------------------------------------------------------
#define NORMC  (-7.62461899f)   /* -log(2048) */
#define LOGN   (6.93147181f)    /* log(1024)  */
#define LOG_MN (7.62461899f)    /* log(2048)  */
#define ZLD    1028
#define SINKB  64               /* blocks in persistent sinkhorn grid */

__device__ __forceinline__ u64 slot_load(const u64* p) {
  return __hip_atomic_load(p, __ATOMIC_RELAXED, __HIP_MEMORY_SCOPE_AGENT);
}
__device__ __forceinline__ void slot_store(u64* p, float v, unsigned gen) {
  union { float f; unsigned u; } c; c.f = v;
  u64 x = ((u64)gen << 32) | (u64)c.u;
  __hip_atomic_store(p, x, __ATOMIC_RELAXED, __HIP_MEMORY_SCOPE_AGENT);
}
__device__ __forceinline__ float slot_val(u64 x) {
  union { unsigned u; float f; } c; c.u = (unsigned)x;
  return c.f;
}

__global__ __launch_bounds__(TPB) void fill_bins(float* __restrict__ Z,
                                                 const float* __restrict__ alpha_p,
                                                 u64* __restrict__ uS,
                                                 u64* __restrict__ vS) {
  float a = *alpha_p;
  int t = blockIdx.x * TPB + threadIdx.x;
  if (t <= 1024) {
    Z[(long)t * ZLD + 1024] = a;
    Z[(long)1024 * ZLD + t] = a;
    slot_store(uS + t, 0.f, 0u);
    slot_store(vS + t, 0.f, 0u);
  }
}

// poll the 17 slots this lane needs until all carry tag == gen
__device__ __forceinline__ void poll_vec(const u64* __restrict__ w, unsigned gen,
                                         int lane, float vv[16], float& w1024) {
  u64 raw[16]; u64 rb;
  bool ok = false;
  while (!ok) {
    ok = true;
#pragma unroll
    for (int t = 0; t < 16; ++t) raw[t] = slot_load(w + lane + 64 * t);
    rb = slot_load(w + 1024);
#pragma unroll
    for (int t = 0; t < 16; ++t)
      if ((unsigned)(raw[t] >> 32) != gen) ok = false;
    if ((unsigned)(rb >> 32) != gen) ok = false;
  }
#pragma unroll
  for (int t = 0; t < 16; ++t) vv[t] = slot_val(raw[t]);
  w1024 = slot_val(rb);
}

// one half-step for 4 register-resident rows + (wave 0) the analytic bin row.
// zreg[r][h][j] holds M[row_r][lane + 64*(8h+j)].
__device__ __forceinline__ void sink_half(const f16x8 zreg[4][2],
                                          const u64* __restrict__ w,
                                          u64* __restrict__ out,
                                          unsigned rgen, int gw, int lane,
                                          float alpha) {
  float vv[16]; float w1024;
  poll_vec(w, rgen, lane, vv, w1024);
  const float binv = alpha + w1024;
  const unsigned wgen = rgen + 1;

#pragma unroll
  for (int r = 0; r < 4; ++r) {
    float val[16];
    float m = binv;
#pragma unroll
    for (int t = 0; t < 16; ++t) {
      val[t] = (float)zreg[r][t >> 3][t & 7] + vv[t];
      m = fmaxf(m, val[t]);
    }
#pragma unroll
    for (int off = 32; off > 0; off >>= 1) m = fmaxf(m, __shfl_xor(m, off));
    float s = 0.f;
#pragma unroll
    for (int t = 0; t < 16; ++t) s += __expf(val[t] - m);
#pragma unroll
    for (int off = 32; off > 0; off >>= 1) s += __shfl_xor(s, off);
    s += __expf(binv - m);
    if (lane == 0)
      slot_store(out + gw + 256 * r, NORMC - (m + logf(s)), wgen);
  }

  if (gw == 0) {
    // bin row: entries alpha + w[j] (j<1024), corner alpha + w[1024]
    float m = w1024;
#pragma unroll
    for (int t = 0; t < 16; ++t) m = fmaxf(m, vv[t]);
#pragma unroll
    for (int off = 32; off > 0; off >>= 1) m = fmaxf(m, __shfl_xor(m, off));
    float s = 0.f;
#pragma unroll
    for (int t = 0; t < 16; ++t) s += __expf(vv[t] - m);
#pragma unroll
    for (int off = 32; off > 0; off >>= 1) s += __shfl_xor(s, off);
    s += __expf(w1024 - m);
    if (lane == 0)
      slot_store(out + 1024, NORMC + LOGN - (alpha + m + logf(s)), wgen);
  }
}

__global__ __launch_bounds__(TPB) void sink_persist(const f16* __restrict__ Zh,
                                                    const f16* __restrict__ Zth,
                                                    u64* __restrict__ uS,
                                                    u64* __restrict__ vS,
                                                    const float* __restrict__ alpha_p) {
  const int lane = threadIdx.x & 63;
  const int gw = blockIdx.x * 4 + (threadIdx.x >> 6);   // 0..255
  const float alpha = *alpha_p;

  // load 4 Z-rows and 4 Zt-rows into registers (read once, kept 100 iters)
  f16x8 zr[4][2], zt[4][2];
#pragma unroll
  for (int r = 0; r < 4; ++r) {
    const long row = gw + 256 * r;
    const f16* zp = Zh + row * ZLD;
    const f16* ztp = Zth + row * ZLD;
#pragma unroll
    for (int h = 0; h < 2; ++h)
#pragma unroll
      for (int j = 0; j < 8; ++j) {
        zr[r][h][j] = zp[lane + 64 * (8 * h + j)];
        zt[r][h][j] = ztp[lane + 64 * (8 * h + j)];
      }
  }

  unsigned gen = 0;
#pragma unroll 1
  for (int it = 0; it < 100; ++it) {
    sink_half(zr, vS, uS, gen, gw, lane, alpha);  ++gen;  // u-step (reads v@gen)
    sink_half(zt, uS, vS, gen, gw, lane, alpha);  ++gen;  // v-step (reads u@gen)
  }
}

__global__ __launch_bounds__(TPB) void assemble(const float* __restrict__ Z,
                                                const u64* __restrict__ uS,
                                                const u64* __restrict__ vS,
                                                float* __restrict__ out) {
  int idx = blockIdx.x * TPB + threadIdx.x;
  if (idx < 1025 * 1025) {
    int i = idx / 1025;
    int j = idx - i * 1025;
    out[idx] = Z[(long)i * ZLD + j] + slot_val(uS[i]) + slot_val(vS[j]) + LOG_MN;
  }
}

// ---------------------------------------------------------------------------
// Host orchestration
// ---------------------------------------------------------------------------
static inline GBH mkgb(const void* A, const void* B, void* C,
                       const float* bias = nullptr, const void* B2 = nullptr,
                       const float* res = nullptr,
                       const float* mu = nullptr, const float* rs = nullptr,
                       int coff = 0, void* o2a = nullptr, void* o2b = nullptr) {
  GBH g; g.A = A; g.B = B; g.B2 = B2; g.C = C; g.bias = bias; g.res = res;
  g.mu = mu; g.rs = rs; g.o2a = o2a; g.o2b = o2b; g.coff = coff; g.pad = 0;
  return g;
}

extern "C" void kernel_launch(void* const* d_in, const int* in_sizes, int n_in,
                              void* d_out, int out_size, void* d_ws, size_t ws_size,
                              hipStream_t stream) {
  const float* kp0     = (const float*)d_in[0];
  const float* kp1     = (const float*)d_in[1];
  const float* desc0   = (const float*)d_in[2];
  const float* desc1   = (const float*)d_in[3];
  const float* sc0     = (const float*)d_in[4];
  const float* sc1     = (const float*)d_in[5];
  const float* kw[4]   = {(const float*)d_in[6], (const float*)d_in[8],
                          (const float*)d_in[10], (const float*)d_in[12]};
  const float* kb[4]   = {(const float*)d_in[7], (const float*)d_in[9],
                          (const float*)d_in[11], (const float*)d_in[13]};
  const float* proj_w  = (const float*)d_in[14];
  const float* proj_b  = (const float*)d_in[15];
  const float* merge_w = (const float*)d_in[16];
  const float* merge_b = (const float*)d_in[17];
  const float* mlp_w0  = (const float*)d_in[18];
  const float* mlp_b0  = (const float*)d_in[19];
  const float* mlp_w1  = (const float*)d_in[20];
  const float* mlp_b1  = (const float*)d_in[21];
  const float* final_w = (const float*)d_in[22];
  const float* final_b = (const float*)d_in[23];
  const float* alpha_p = (const float*)d_in[24];

  float* p = (float*)d_ws;
  float* dA  = p; p += 524288;
  float* dB  = p; p += 524288;
  float* h0  = p; p += 8192;
  float* hb1 = p; p += 262144;
  float* hb2 = p; p += 131072;
  float* msg = p; p += 524288;
  float* muA = p; p += 1024;
  float* rsA = p; p += 1024;
  float* Mrw = p; p += 8192;
  float* Inv = p; p += 8192;
  float* Zb  = p; p += 1053700;
  u64* uS = (u64*)p; p += 2050;        // 1025 x 8B slots (gen|value)
  u64* vS = (u64*)p; p += 2050;
  f16* qkvh = (f16*)p; p += 786432;   // 6 x 256 x 1024 f16
  f16* Sh   = (f16*)p; p += 4194304;  // 8 x 1024 x 1024 f16
  f16* oAh  = (f16*)p; p += 262144;   // 2 x 1024 x 256 f16
  f16* oBh  = (f16*)p; p += 262144;
  f16* tbh  = (f16*)p; p += 524288;   // 2 x 512 x 1024 f16
  f16* mdbh = (f16*)p; p += 262144;   // 2 x 256 x 1024 f16
  f16* Zh   = (f16*)p; p += 526852;
  f16* Zth  = (f16*)p; p += 526852;
  size_t need_bytes = (size_t)(p - (float*)d_ws) * sizeof(float);
  if (ws_size < need_bytes) return;

  const long DSTR = 262144;

  // ---- keypoint encoder ----
  build_h0<<<dim3(4, 2), TPB, 0, stream>>>(kp0, kp1, sc0, sc1, h0);
  chanconv<true, false><<<dim3(32, 2),  TPB, 0, stream>>>(kw[0], kb[0], h0,  4096,   nullptr, nullptr, hb1, 32768,  4);
  chanconv<true, false><<<dim3(64, 2),  TPB, 0, stream>>>(kw[1], kb[1], hb1, 32768,  nullptr, nullptr, hb2, 65536,  32);
  chanconv<true, false><<<dim3(128, 2), TPB, 0, stream>>>(kw[2], kb[2], hb2, 65536,  nullptr, nullptr, hb1, 131072, 64);
  chanconv<false, true><<<dim3(256, 2), TPB, 0, stream>>>(kw[3], kb[3], hb1, 131072, desc0,   desc1,   dA,  DSTR,   128);

  // ---- GNN layers ----
  float* dc = dA;
  float* dn = dB;
  for (int i = 0; i < 18; ++i) {
    bool cross = (i & 1) != 0;
    const float* xs[2] = {dc, dc + DSTR};
    const float* ss2[2] = {cross ? xs[1] : xs[0], cross ? xs[0] : xs[1]};

    // K1: q/k/v projections -> qkvh f16
    {
      GB16 gb{};
      for (int im = 0; im < 2; ++im)
        for (int pp = 0; pp < 3; ++pp)
          gb.g[im * 3 + pp] = mkgb(proj_w + (size_t)(i * 3 + pp) * 65536,
                                   (pp == 0 ? xs[im] : ss2[im]),
                                   qkvh + (size_t)(im * 3 + pp) * DSTR,
                                   proj_b + (size_t)(i * 3 + pp) * 256);
      gemmh<128, 0, 0, F_CD16><<<dim3(8, 4, 6), TPB, 0, stream>>>(
          gb, 256, 256, 1024, 1024, 1.f, 0);
    }
    // K2: S = q^T k / 8 -> Sh f16
    {
      GB16 gb{};
      for (int im = 0; im < 2; ++im)
        for (int h = 0; h < 4; ++h)
          gb.g[im * 4 + h] = mkgb(qkvh + (size_t)(im * 3 + 0) * DSTR + h * 1024,
                                  qkvh + (size_t)(im * 3 + 1) * DSTR + h * 1024,
                                  Sh + (size_t)(im * 4 + h) * 1048576);
      gemmh<128, 1, 1, F_CD16><<<dim3(8, 16, 8), TPB, 0, stream>>>(
          gb, 64, 4096, 4096, 1024, 0.125f, 0);
    }
    // K3: per-row softmax stats
    rowlse_h<<<2048, TPB, 0, stream>>>(Sh, Mrw, Inv);
    // K4T: oT[pos][4*d+h] = sum_kv P * v ; K split in halves -> oAh/oBh
    {
      GB16 gb{};
      for (int kh = 0; kh < 2; ++kh)
        for (int imh = 0; imh < 8; ++imh) {
          int im = imh >> 2, h = imh & 3;
          gb.g[kh * 8 + imh] = mkgb(Sh + (size_t)imh * 1048576 + kh * 512,
                                    qkvh + (size_t)(im * 3 + 2) * DSTR + h * 1024 + kh * 512,
                                    (kh ? oBh : oAh) + (size_t)im * 262144,
                                    nullptr, nullptr, nullptr,
                                    Mrw + imh * 1024, Inv + imh * 1024, h);
        }
      gemmh<64, 2, 2, F_CD16 | F_CSCAT><<<dim3(1, 16, 16), TPB, 0, stream>>>(
          gb, 512, 1024, 4096, 256, 1.f, 0);
    }
    // K5: merge (adds the two K-half partials) -> msg fp32
    {
      GB16 gb{};
      for (int im = 0; im < 2; ++im)
        gb.g[im] = mkgb(merge_w + (size_t)i * 65536, oAh + (size_t)im * 262144,
                        msg + (size_t)im * DSTR, merge_b + (size_t)i * 256,
                        oBh + (size_t)im * 262144);
      gemmh<64, 0, 2, F_BADD><<<dim3(16, 4, 2), TPB, 0, stream>>>(
          gb, 256, 256, 256, 1024, 1.f, 0);
    }
    // K6: mlp0 on concat([x, msg]) -> tbh f16
    {
      GB16 gb{};
      for (int im = 0; im < 2; ++im)
        gb.g[im] = mkgb(mlp_w0 + (size_t)i * 262144, xs[im],
                        tbh + (size_t)im * 524288, mlp_b0 + (size_t)i * 512,
                        msg + (size_t)im * DSTR);
      gemmh<64, 0, 0, F_BCONCAT | F_CD16><<<dim3(16, 8, 2), TPB, 0, stream>>>(
          gb, 512, 512, 1024, 1024, 1.f, 256);
    }
    // K7: per-channel inorm stats
    rowstats2_h<<<256, TPB, 0, stream>>>(tbh, muA, rsA);
    // K8: mlp1 with fused inorm+relu on B, fp32 residual -> dn
    {
      GB16 gb{};
      for (int im = 0; im < 2; ++im)
        gb.g[im] = mkgb(mlp_w1 + (size_t)i * 131072, tbh + (size_t)im * 524288,
                        dn + (size_t)im * DSTR, mlp_b1 + (size_t)i * 256,
                        nullptr, xs[im],
                        muA + (size_t)im * 512, rsA + (size_t)im * 512);
      gemmh<64, 0, 1, F_BNORM | F_RES><<<dim3(16, 4, 2), TPB, 0, stream>>>(
          gb, 512, 512, 1024, 1024, 1.f, 0);
    }
    float* tmp = dc; dc = dn; dn = tmp;
  }

  // ---- final projection -> mdbh f16 ----
  {
    GB16 gb{};
    for (int im = 0; im < 2; ++im)
      gb.g[im] = mkgb(final_w, dc + (size_t)im * DSTR, mdbh + (size_t)im * 262144,
                      final_b);
    gemmh<64, 0, 0, F_CD16><<<dim3(16, 4, 2), TPB, 0, stream>>>(
        gb, 256, 256, 1024, 1024, 1.f, 0);
  }
  // ---- scores -> Zb fp32 + Zh/Zth f16 ----
  {
    GB16 gb{};
    gb.g[0] = mkgb(mdbh, mdbh + 262144, Zb, nullptr, nullptr, nullptr,
                   nullptr, nullptr, 0, Zh, Zth);
    gemmh<64, 1, 1, F_OUT2><<<dim3(16, 16, 1), TPB, 0, stream>>>(
        gb, 256, 1024, 1024, ZLD, 0.0625f, 0);
  }
  fill_bins<<<5, TPB, 0, stream>>>(Zb, alpha_p, uS, vS);

  // ---- Sinkhorn: one persistent kernel, barrier-free dataflow ----
  sink_persist<<<SINKB, TPB, 0, stream>>>(Zh, Zth, uS, vS, alpha_p);

  // ---- output ----
  assemble<<<4105, TPB, 0, stream>>>(Zb, uS, vS, (float*)d_out);
}

// Round 7
// 2282.663 us; speedup vs baseline: 1.1659x; 1.1659x over previous
//
#include <hip/hip_runtime.h>
#include <cstddef>

#define TPB 256

typedef _Float16 f16;
typedef _Float16 f16x4 __attribute__((ext_vector_type(4)));
typedef _Float16 f16x8 __attribute__((ext_vector_type(8)));
typedef float f32x4 __attribute__((ext_vector_type(4)));
typedef unsigned long long u64;

// ---------------------------------------------------------------------------
// block reduction (for chanconv)
// ---------------------------------------------------------------------------
__device__ __forceinline__ float block_sum(float v, float* red) {
  int tid = threadIdx.x;
  red[tid] = v; __syncthreads();
#pragma unroll
  for (int off = 128; off > 0; off >>= 1) {
    if (tid < off) red[tid] += red[tid + off];
    __syncthreads();
  }
  float r = red[0];
  __syncthreads();
  return r;
}

// ---------------------------------------------------------------------------
// h0 build: h0[im][4][1024]
// ---------------------------------------------------------------------------
__global__ __launch_bounds__(TPB) void build_h0(const float* __restrict__ kp0,
                                                const float* __restrict__ kp1,
                                                const float* __restrict__ sc0,
                                                const float* __restrict__ sc1,
                                                float* __restrict__ h0) {
  int n = blockIdx.x * TPB + threadIdx.x;
  int im = blockIdx.y;
  const float* kp = im ? kp1 : kp0;
  const float* sc = im ? sc1 : sc0;
  float* h = h0 + (size_t)im * 4096;
  h[n]        = kp[n * 3 + 0];
  h[1024 + n] = kp[n * 3 + 1];
  h[2048 + n] = kp[n * 3 + 2];
  h[3072 + n] = sc[n];
}

// ---------------------------------------------------------------------------
// kenc conv layer (fp32, small)
// ---------------------------------------------------------------------------
template<bool NORMRELU, bool RESID>
__global__ __launch_bounds__(TPB) void chanconv(const float* __restrict__ W,
                                                const float* __restrict__ bias,
                                                const float* __restrict__ in, long instride,
                                                const float* res0, const float* res1,
                                                float* __restrict__ out, long outstride, int C) {
  int o = blockIdx.x, im = blockIdx.y, tid = threadIdx.x;
  const float* inp = in + (long)im * instride;
  __shared__ float Ws[128];
  __shared__ float red[TPB];
  for (int c = tid; c < C; c += TPB) Ws[c] = W[(long)o * C + c];
  __syncthreads();
  float b = bias[o];
  float4 acc = {b, b, b, b};
  for (int c = 0; c < C; ++c) {
    float w = Ws[c];
    float4 v = *(const float4*)(inp + (long)c * 1024 + tid * 4);
    acc.x += w * v.x; acc.y += w * v.y; acc.z += w * v.z; acc.w += w * v.w;
  }
  float* orow = out + (long)im * outstride + (long)o * 1024;
  if (NORMRELU) {
    float s = acc.x + acc.y + acc.z + acc.w;
    float mean = block_sum(s, red) * (1.f / 1024.f);
    float dx = acc.x - mean, dy = acc.y - mean, dz = acc.z - mean, dw = acc.w - mean;
    float var = block_sum(dx * dx + dy * dy + dz * dz + dw * dw, red) * (1.f / 1024.f);
    float rstd = rsqrtf(var + 1e-5f);
    float4 o4 = {fmaxf(dx * rstd, 0.f), fmaxf(dy * rstd, 0.f),
                 fmaxf(dz * rstd, 0.f), fmaxf(dw * rstd, 0.f)};
    *(float4*)(orow + tid * 4) = o4;
  } else {
    if (RESID) {
      const float* res = im ? res1 : res0;
      float4 r = *(const float4*)(res + (long)o * 1024 + tid * 4);
      acc.x += r.x; acc.y += r.y; acc.z += r.z; acc.w += r.w;
    }
    *(float4*)(orow + tid * 4) = acc;
  }
}

// ---------------------------------------------------------------------------
// fp16-MFMA batched GEMM. Block BMxBN, 4 waves, wave (BM==64? 2x2 : 1x4).
// MFMA v_mfma_f32_16x16x16_f16; A-frag lane l: row=l&15, k=4*(l>>4)+j;
// B-frag: col=l&15, same k; D: col=l&15, row=4*(l>>4)+reg.
// LDS: As[m][k] / Bs[n][k] with k-contiguous rows, pitch 36 f16.
//   ASRC 0: fp32 [m][k]   1: f16 [k][m]   2: f16 [m][k] + softmax exp (mu=M, rs=inv)
//   BSRC 0: fp32 [k][n] (+concat B2)   1: f16 [k][n] (+inorm-relu)   2: f16 [n][k] (+add B2)
// ---------------------------------------------------------------------------
struct GBH {
  const void* A; const void* B; const void* B2; void* C;
  const float* bias; const float* res; const float* mu; const float* rs;
  void* o2a; void* o2b; int coff; int pad;
};
struct GB16 { GBH g[16]; };

#define F_BNORM   1
#define F_BCONCAT 2
#define F_BADD    4
#define F_CD16    8
#define F_RES     16
#define F_OUT2    32
#define F_CSCAT   64

template<int BM, int BN, int ASRC, int BSRC, int FLAGS>
__global__ __launch_bounds__(TPB) void gemmh(GB16 gbs, int K, int lda, int ldb,
                                             int ldc, float alpha, int ksplit) {
  constexpr int WM = BM / 32;          // 2 or 1
  constexpr int NWN = 4 / WM;          // waves along N: 2 or 4
  constexpr int WN = BN / NWN;
  constexpr int NFR = WN / 16;
  GBH g = gbs.g[blockIdx.z];
  const int tid = threadIdx.x;
  const int lane = tid & 63, wid = tid >> 6;
  const int wm = wid / NWN, wn = wid % NWN;
  const int m0 = blockIdx.y * BM, n0 = blockIdx.x * BN;
  __shared__ f16 As[BM][36];
  __shared__ f16 Bs[BN][36];
  f32x4 acc[2][NFR];
#pragma unroll
  for (int i = 0; i < 2; ++i)
#pragma unroll
    for (int j = 0; j < NFR; ++j) acc[i][j] = (f32x4){0.f, 0.f, 0.f, 0.f};

  for (int k0 = 0; k0 < K; k0 += 32) {
    // ---- stage A ----
    if constexpr (ASRC == 0) {
      if constexpr (BM == 64) {
        const int m = tid >> 2, k4 = (tid & 3) * 8;
        const float* ap = (const float*)g.A + (long)(m0 + m) * lda + k0 + k4;
        float4 u0 = *(const float4*)ap, u1 = *(const float4*)(ap + 4);
        f16x4 h0 = {(f16)u0.x, (f16)u0.y, (f16)u0.z, (f16)u0.w};
        f16x4 h1 = {(f16)u1.x, (f16)u1.y, (f16)u1.z, (f16)u1.w};
        *(f16x4*)&As[m][k4] = h0;
        *(f16x4*)&As[m][k4 + 4] = h1;
      } else {
        const int m = tid >> 3, k4 = (tid & 7) * 4;
        const float* ap = (const float*)g.A + (long)(m0 + m) * lda + k0 + k4;
        float4 u0 = *(const float4*)ap;
        f16x4 h0 = {(f16)u0.x, (f16)u0.y, (f16)u0.z, (f16)u0.w};
        *(f16x4*)&As[m][k4] = h0;
      }
    } else if constexpr (ASRC == 1) {
      const int k = tid >> 3, mg = (tid & 7) * 8;
      const f16* ap = (const f16*)g.A + (long)(k0 + k) * lda + m0 + mg;
      f16x8 h = *(const f16x8*)ap;
#pragma unroll
      for (int j = 0; j < 8; ++j) As[mg + j][k] = h[j];
    } else {
      const int m = tid >> 2, k4 = (tid & 3) * 8;
      const f16* ap = (const f16*)g.A + (long)(m0 + m) * lda + k0 + k4;
      f16x8 h = *(const f16x8*)ap;
      const float M = g.mu[m0 + m], Iv = g.rs[m0 + m];
      f16x4 h0, h1;
#pragma unroll
      for (int j = 0; j < 4; ++j) h0[j] = (f16)(__expf((float)h[j] - M) * Iv);
#pragma unroll
      for (int j = 0; j < 4; ++j) h1[j] = (f16)(__expf((float)h[j + 4] - M) * Iv);
      *(f16x4*)&As[m][k4] = h0;
      *(f16x4*)&As[m][k4 + 4] = h1;
    }
    // ---- stage B ----
#pragma unroll
    for (int r = 0; r < BN / 64; ++r) {
      if constexpr (BSRC == 0) {
        const int k = tid >> 3, ng = (tid & 7) * 8 + r * 64;
        const int kg = k0 + k;
        const float* bp;
        if constexpr ((FLAGS & F_BCONCAT) != 0)
          bp = (kg < ksplit) ? ((const float*)g.B + (long)kg * ldb)
                             : ((const float*)g.B2 + (long)(kg - ksplit) * ldb);
        else
          bp = (const float*)g.B + (long)kg * ldb;
        float4 u0 = *(const float4*)(bp + n0 + ng);
        float4 u1 = *(const float4*)(bp + n0 + ng + 4);
        Bs[ng + 0][k] = (f16)u0.x; Bs[ng + 1][k] = (f16)u0.y;
        Bs[ng + 2][k] = (f16)u0.z; Bs[ng + 3][k] = (f16)u0.w;
        Bs[ng + 4][k] = (f16)u1.x; Bs[ng + 5][k] = (f16)u1.y;
        Bs[ng + 6][k] = (f16)u1.z; Bs[ng + 7][k] = (f16)u1.w;
      } else if constexpr (BSRC == 1) {
        const int k = tid >> 3, ng = (tid & 7) * 8 + r * 64;
        const int kg = k0 + k;
        f16x8 h = *(const f16x8*)((const f16*)g.B + (long)kg * ldb + n0 + ng);
        if constexpr ((FLAGS & F_BNORM) != 0) {
          const float mu = g.mu[kg], rs = g.rs[kg];
#pragma unroll
          for (int j = 0; j < 8; ++j)
            h[j] = (f16)fmaxf(((float)h[j] - mu) * rs, 0.f);
        }
#pragma unroll
        for (int j = 0; j < 8; ++j) Bs[ng + j][k] = h[j];
      } else {
        const int n = (tid >> 2) + r * 64, k4 = (tid & 3) * 8;
        const f16* bp = (const f16*)g.B + (long)(n0 + n) * ldb + k0 + k4;
        f16x8 h = *(const f16x8*)bp;
        if constexpr ((FLAGS & F_BADD) != 0) {
          f16x8 h2 = *(const f16x8*)((const f16*)g.B2 + (long)(n0 + n) * ldb + k0 + k4);
          h = h + h2;
        }
        f16x4 h0 = {h[0], h[1], h[2], h[3]};
        f16x4 h1 = {h[4], h[5], h[6], h[7]};
        *(f16x4*)&Bs[n][k4] = h0;
        *(f16x4*)&Bs[n][k4 + 4] = h1;
      }
    }
    __syncthreads();
    // ---- MFMA ----
#pragma unroll
    for (int ks = 0; ks < 2; ++ks) {
      const int kof = ks * 16 + ((lane >> 4) << 2);
      f16x4 a[2], b[NFR];
      a[0] = *(const f16x4*)&As[wm * 32 + (lane & 15)][kof];
      a[1] = *(const f16x4*)&As[wm * 32 + 16 + (lane & 15)][kof];
#pragma unroll
      for (int fn = 0; fn < NFR; ++fn)
        b[fn] = *(const f16x4*)&Bs[wn * WN + fn * 16 + (lane & 15)][kof];
#pragma unroll
      for (int fm = 0; fm < 2; ++fm)
#pragma unroll
        for (int fn = 0; fn < NFR; ++fn)
          acc[fm][fn] = __builtin_amdgcn_mfma_f32_16x16x16f16(a[fm], b[fn], acc[fm][fn], 0, 0, 0);
    }
    __syncthreads();
  }

  // ---- epilogue ----
  const int r0 = (lane >> 4) << 2, cn = lane & 15;
#pragma unroll
  for (int fm = 0; fm < 2; ++fm) {
#pragma unroll
    for (int r = 0; r < 4; ++r) {
      const int m = m0 + wm * 32 + fm * 16 + r0 + r;
      const float bi = g.bias ? g.bias[m] : 0.f;
#pragma unroll
      for (int fn = 0; fn < NFR; ++fn) {
        const int n = n0 + wn * WN + fn * 16 + cn;
        float v = acc[fm][fn][r] * alpha + bi;
        if constexpr ((FLAGS & F_RES) != 0) v += g.res[(long)m * ldc + n];
        if constexpr ((FLAGS & F_OUT2) != 0) {
          ((float*)g.C)[(long)m * 1028 + n] = v;
          ((f16*)g.o2a)[(long)m * 1028 + n] = (f16)v;
          ((f16*)g.o2b)[(long)n * 1028 + m] = (f16)v;
        } else if constexpr ((FLAGS & F_CSCAT) != 0) {
          ((f16*)g.C)[(long)m * ldc + g.coff + 4 * n] = (f16)v;
        } else if constexpr ((FLAGS & F_CD16) != 0) {
          ((f16*)g.C)[(long)m * ldc + n] = (f16)v;
        } else {
          ((float*)g.C)[(long)m * ldc + n] = v;
        }
      }
    }
  }
}

// ---------------------------------------------------------------------------
// rowlse over f16 S rows (1024 wide): Mrow, Inv = 1/sum(exp(x-M)). Wave/row.
// ---------------------------------------------------------------------------
__global__ __launch_bounds__(TPB) void rowlse_h(const f16* __restrict__ S,
                                                float* __restrict__ Mrow,
                                                float* __restrict__ Inv) {
  int row = blockIdx.x * 4 + (threadIdx.x >> 6);
  int lane = threadIdx.x & 63;
  const f16x8* p = (const f16x8*)(S + (long)row * 1024);
  f16x8 v0 = p[lane], v1 = p[lane + 64];
  float m = -1e30f;
#pragma unroll
  for (int j = 0; j < 8; ++j)
    m = fmaxf(m, fmaxf((float)v0[j], (float)v1[j]));
#pragma unroll
  for (int off = 32; off > 0; off >>= 1) m = fmaxf(m, __shfl_xor(m, off));
  float s = 0.f;
#pragma unroll
  for (int j = 0; j < 8; ++j)
    s += __expf((float)v0[j] - m) + __expf((float)v1[j] - m);
#pragma unroll
  for (int off = 32; off > 0; off >>= 1) s += __shfl_xor(s, off);
  if (lane == 0) { Mrow[row] = m; Inv[row] = 1.f / s; }
}

// ---------------------------------------------------------------------------
// rowstats over f16 tb rows (1024 wide): mean, rsqrt(var+eps). Wave/row.
// ---------------------------------------------------------------------------
__global__ __launch_bounds__(TPB) void rowstats2_h(const f16* __restrict__ t,
                                                   float* __restrict__ mu,
                                                   float* __restrict__ rs) {
  int row = blockIdx.x * 4 + (threadIdx.x >> 6);
  int lane = threadIdx.x & 63;
  const f16x8* p = (const f16x8*)(t + (long)row * 1024);
  f16x8 v0 = p[lane], v1 = p[lane + 64];
  float s = 0.f, s2 = 0.f;
#pragma unroll
  for (int j = 0; j < 8; ++j) {
    float a = (float)v0[j], b = (float)v1[j];
    s += a + b; s2 += a * a + b * b;
  }
#pragma unroll
  for (int off = 32; off > 0; off >>= 1) { s += __shfl_xor(s, off); s2 += __shfl_xor(s2, off); }
  if (lane == 0) {
    float mean = s * (1.f / 1024.f);
    mu[row] = mean;
    rs[row] = rsqrtf(fmaxf(s2 * (1.f / 1024.f) - mean * mean, 0.f) + 1e-5f);
  }
}

// ---------------------------------------------------------------------------
// Sinkhorn — persistent, Z in registers. Relaxed-only grid barrier (r5 design)
// + block-consolidated consume: after the barrier, each BLOCK loads the u/v
// vector once (u64 relaxed agent-scope atomic loads, bypassing the stale-able
// per-XCD L2s) into LDS; all 4 waves read LDS. Producers store packed u64
// value pairs (wave gw owns contiguous rows [4gw, 4gw+4)).
// __syncthreads' mandatory vmcnt-drain before s_barrier guarantees this
// block's value stores reached the LLC before its barrier arrival is counted.
// ---------------------------------------------------------------------------
#define NORMC  (-7.62461899f)   /* -log(2048) */
#define LOGN   (6.93147181f)    /* log(1024)  */
#define LOG_MN (7.62461899f)    /* log(2048)  */
#define ZLD    1028
#define SINKB  64               /* blocks in persistent sinkhorn grid */

__device__ __forceinline__ u64 llc_load64(const u64* p) {
  return __hip_atomic_load(p, __ATOMIC_RELAXED, __HIP_MEMORY_SCOPE_AGENT);
}
__device__ __forceinline__ void llc_store64(u64* p, u64 v) {
  __hip_atomic_store(p, v, __ATOMIC_RELAXED, __HIP_MEMORY_SCOPE_AGENT);
}
__device__ __forceinline__ void llc_store32(float* p, float v) {
  __hip_atomic_store(p, v, __ATOMIC_RELAXED, __HIP_MEMORY_SCOPE_AGENT);
}
__device__ __forceinline__ u64 pack2(float a, float b) {
  union { float f[2]; u64 x; } c; c.f[0] = a; c.f[1] = b; return c.x;
}

__global__ __launch_bounds__(TPB) void fill_bins(float* __restrict__ Z,
                                                 const float* __restrict__ alpha_p,
                                                 float* __restrict__ vF,
                                                 unsigned* __restrict__ bar) {
  float a = *alpha_p;
  int t = blockIdx.x * TPB + threadIdx.x;
  if (t < ZLD) vF[t] = 0.f;
  if (t == 0) *bar = 0u;
  if (t <= 1024) {
    Z[(long)t * ZLD + 1024] = a;
    Z[(long)1024 * ZLD + t] = a;
  }
}

// relaxed-only grid barrier (monotonic counter, gen*SINKB target)
__device__ __forceinline__ void gridbar(unsigned* __restrict__ bar, unsigned gen) {
  __syncthreads();
  if (threadIdx.x == 0) {
    __hip_atomic_fetch_add(bar, 1u, __ATOMIC_RELAXED, __HIP_MEMORY_SCOPE_AGENT);
    const unsigned target = gen * SINKB;
    while (__hip_atomic_load(bar, __ATOMIC_RELAXED, __HIP_MEMORY_SCOPE_AGENT) < target) {}
  }
  asm volatile("" ::: "memory");
  __syncthreads();
}

// one half-step: block-consume w into LDS, compute 4 rows/wave (+ bin row on
// wave 0), store packed results.
__device__ __forceinline__ void sink_half(const f16x8 zreg[4][2],
                                          const float* __restrict__ w,
                                          float* __restrict__ out,
                                          int tid, int gw, int lane,
                                          float alpha, float* __restrict__ lds) {
  // block-wide consume: 513 u64 (f32 0..1025), single pass, guaranteed fresh
  for (int s = tid; s < 513; s += TPB) {
    u64 x = llc_load64((const u64*)w + s);
    union { u64 x; float f[2]; } c; c.x = x;
    lds[2 * s] = c.f[0];
    lds[2 * s + 1] = c.f[1];
  }
  __syncthreads();
  float vv[16];
#pragma unroll
  for (int t = 0; t < 16; ++t) vv[t] = lds[lane + 64 * t];
  const float w1024 = lds[1024];
  const float binv = alpha + w1024;

  float res[4];
#pragma unroll
  for (int r = 0; r < 4; ++r) {
    float val[16];
    float m = binv;
#pragma unroll
    for (int t = 0; t < 16; ++t) {
      val[t] = (float)zreg[r][t >> 3][t & 7] + vv[t];
      m = fmaxf(m, val[t]);
    }
#pragma unroll
    for (int off = 32; off > 0; off >>= 1) m = fmaxf(m, __shfl_xor(m, off));
    float s = 0.f;
#pragma unroll
    for (int t = 0; t < 16; ++t) s += __expf(val[t] - m);
#pragma unroll
    for (int off = 32; off > 0; off >>= 1) s += __shfl_xor(s, off);
    s += __expf(binv - m);
    res[r] = NORMC - (m + logf(s));
  }
  if (lane < 2)
    llc_store64((u64*)(out + 4 * gw) + lane, pack2(res[2 * lane], res[2 * lane + 1]));

  if (gw == 0) {
    // bin row: entries alpha + w[j] (j<1024), corner alpha + w[1024]
    float m = w1024;
#pragma unroll
    for (int t = 0; t < 16; ++t) m = fmaxf(m, vv[t]);
#pragma unroll
    for (int off = 32; off > 0; off >>= 1) m = fmaxf(m, __shfl_xor(m, off));
    float s = 0.f;
#pragma unroll
    for (int t = 0; t < 16; ++t) s += __expf(vv[t] - m);
#pragma unroll
    for (int off = 32; off > 0; off >>= 1) s += __shfl_xor(s, off);
    s += __expf(w1024 - m);
    if (lane == 0)
      llc_store32(out + 1024, NORMC + LOGN - (alpha + m + logf(s)));
  }
}

__global__ __launch_bounds__(TPB) void sink_persist(const f16* __restrict__ Zh,
                                                    const f16* __restrict__ Zth,
                                                    float* __restrict__ uF,
                                                    float* __restrict__ vF,
                                                    unsigned* __restrict__ bar,
                                                    const float* __restrict__ alpha_p) {
  __shared__ float lds[ZLD];
  const int tid = threadIdx.x;
  const int lane = tid & 63;
  const int gw = blockIdx.x * 4 + (tid >> 6);   // 0..255, owns rows [4gw,4gw+4)
  const float alpha = *alpha_p;

  // load 4 Z-rows and 4 Zt-rows into registers (read once, kept 100 iters)
  f16x8 zr[4][2], zt[4][2];
#pragma unroll
  for (int r = 0; r < 4; ++r) {
    const long row = 4 * gw + r;
    const f16* zp = Zh + row * ZLD;
    const f16* ztp = Zth + row * ZLD;
#pragma unroll
    for (int h = 0; h < 2; ++h)
#pragma unroll
      for (int j = 0; j < 8; ++j) {
        zr[r][h][j] = zp[lane + 64 * (8 * h + j)];
        zt[r][h][j] = ztp[lane + 64 * (8 * h + j)];
      }
  }

  unsigned gen = 0;
#pragma unroll 1
  for (int it = 0; it < 100; ++it) {
    sink_half(zr, vF, uF, tid, gw, lane, alpha, lds);   // u-step (reads v)
    gridbar(bar, ++gen);
    sink_half(zt, uF, vF, tid, gw, lane, alpha, lds);   // v-step (reads u)
    gridbar(bar, ++gen);
  }
}

__global__ __launch_bounds__(TPB) void assemble(const float* __restrict__ Z,
                                                const float* __restrict__ u,
                                                const float* __restrict__ v,
                                                float* __restrict__ out) {
  int idx = blockIdx.x * TPB + threadIdx.x;
  if (idx < 1025 * 1025) {
    int i = idx / 1025;
    int j = idx - i * 1025;
    out[idx] = Z[(long)i * ZLD + j] + u[i] + v[j] + LOG_MN;
  }
}

// ---------------------------------------------------------------------------
// Host orchestration
// ---------------------------------------------------------------------------
static inline GBH mkgb(const void* A, const void* B, void* C,
                       const float* bias = nullptr, const void* B2 = nullptr,
                       const float* res = nullptr,
                       const float* mu = nullptr, const float* rs = nullptr,
                       int coff = 0, void* o2a = nullptr, void* o2b = nullptr) {
  GBH g; g.A = A; g.B = B; g.B2 = B2; g.C = C; g.bias = bias; g.res = res;
  g.mu = mu; g.rs = rs; g.o2a = o2a; g.o2b = o2b; g.coff = coff; g.pad = 0;
  return g;
}

extern "C" void kernel_launch(void* const* d_in, const int* in_sizes, int n_in,
                              void* d_out, int out_size, void* d_ws, size_t ws_size,
                              hipStream_t stream) {
  const float* kp0     = (const float*)d_in[0];
  const float* kp1     = (const float*)d_in[1];
  const float* desc0   = (const float*)d_in[2];
  const float* desc1   = (const float*)d_in[3];
  const float* sc0     = (const float*)d_in[4];
  const float* sc1     = (const float*)d_in[5];
  const float* kw[4]   = {(const float*)d_in[6], (const float*)d_in[8],
                          (const float*)d_in[10], (const float*)d_in[12]};
  const float* kb[4]   = {(const float*)d_in[7], (const float*)d_in[9],
                          (const float*)d_in[11], (const float*)d_in[13]};
  const float* proj_w  = (const float*)d_in[14];
  const float* proj_b  = (const float*)d_in[15];
  const float* merge_w = (const float*)d_in[16];
  const float* merge_b = (const float*)d_in[17];
  const float* mlp_w0  = (const float*)d_in[18];
  const float* mlp_b0  = (const float*)d_in[19];
  const float* mlp_w1  = (const float*)d_in[20];
  const float* mlp_b1  = (const float*)d_in[21];
  const float* final_w = (const float*)d_in[22];
  const float* final_b = (const float*)d_in[23];
  const float* alpha_p = (const float*)d_in[24];

  float* p = (float*)d_ws;
  float* dA  = p; p += 524288;
  float* dB  = p; p += 524288;
  float* h0  = p; p += 8192;
  float* hb1 = p; p += 262144;
  float* hb2 = p; p += 131072;
  float* msg = p; p += 524288;
  float* muA = p; p += 1024;
  float* rsA = p; p += 1024;
  float* Mrw = p; p += 8192;
  float* Inv = p; p += 8192;
  float* Zb  = p; p += 1053700;
  float* uF  = p; p += 1028;           // u vector (f32, 8B-aligned)
  float* vF  = p; p += 1028;
  unsigned* bar = (unsigned*)p; p += 4;
  f16* qkvh = (f16*)p; p += 786432;   // 6 x 256 x 1024 f16
  f16* Sh   = (f16*)p; p += 4194304;  // 8 x 1024 x 1024 f16
  f16* oAh  = (f16*)p; p += 262144;   // 2 x 1024 x 256 f16
  f16* oBh  = (f16*)p; p += 262144;
  f16* tbh  = (f16*)p; p += 524288;   // 2 x 512 x 1024 f16
  f16* mdbh = (f16*)p; p += 262144;   // 2 x 256 x 1024 f16
  f16* Zh   = (f16*)p; p += 526852;
  f16* Zth  = (f16*)p; p += 526852;
  size_t need_bytes = (size_t)(p - (float*)d_ws) * sizeof(float);
  if (ws_size < need_bytes) return;

  const long DSTR = 262144;

  // ---- keypoint encoder ----
  build_h0<<<dim3(4, 2), TPB, 0, stream>>>(kp0, kp1, sc0, sc1, h0);
  chanconv<true, false><<<dim3(32, 2),  TPB, 0, stream>>>(kw[0], kb[0], h0,  4096,   nullptr, nullptr, hb1, 32768,  4);
  chanconv<true, false><<<dim3(64, 2),  TPB, 0, stream>>>(kw[1], kb[1], hb1, 32768,  nullptr, nullptr, hb2, 65536,  32);
  chanconv<true, false><<<dim3(128, 2), TPB, 0, stream>>>(kw[2], kb[2], hb2, 65536,  nullptr, nullptr, hb1, 131072, 64);
  chanconv<false, true><<<dim3(256, 2), TPB, 0, stream>>>(kw[3], kb[3], hb1, 131072, desc0,   desc1,   dA,  DSTR,   128);

  // ---- GNN layers ----
  float* dc = dA;
  float* dn = dB;
  for (int i = 0; i < 18; ++i) {
    bool cross = (i & 1) != 0;
    const float* xs[2] = {dc, dc + DSTR};
    const float* ss2[2] = {cross ? xs[1] : xs[0], cross ? xs[0] : xs[1]};

    // K1: q/k/v projections -> qkvh f16 (BM=32 -> 384 blocks)
    {
      GB16 gb{};
      for (int im = 0; im < 2; ++im)
        for (int pp = 0; pp < 3; ++pp)
          gb.g[im * 3 + pp] = mkgb(proj_w + (size_t)(i * 3 + pp) * 65536,
                                   (pp == 0 ? xs[im] : ss2[im]),
                                   qkvh + (size_t)(im * 3 + pp) * DSTR,
                                   proj_b + (size_t)(i * 3 + pp) * 256);
      gemmh<32, 128, 0, 0, F_CD16><<<dim3(8, 8, 6), TPB, 0, stream>>>(
          gb, 256, 256, 1024, 1024, 1.f, 0);
    }
    // K2: S = q^T k / 8 -> Sh f16
    {
      GB16 gb{};
      for (int im = 0; im < 2; ++im)
        for (int h = 0; h < 4; ++h)
          gb.g[im * 4 + h] = mkgb(qkvh + (size_t)(im * 3 + 0) * DSTR + h * 1024,
                                  qkvh + (size_t)(im * 3 + 1) * DSTR + h * 1024,
                                  Sh + (size_t)(im * 4 + h) * 1048576);
      gemmh<64, 128, 1, 1, F_CD16><<<dim3(8, 16, 8), TPB, 0, stream>>>(
          gb, 64, 4096, 4096, 1024, 0.125f, 0);
    }
    // K3: per-row softmax stats
    rowlse_h<<<2048, TPB, 0, stream>>>(Sh, Mrw, Inv);
    // K4T: oT[pos][4*d+h] = sum_kv P * v ; K split in halves -> oAh/oBh
    {
      GB16 gb{};
      for (int kh = 0; kh < 2; ++kh)
        for (int imh = 0; imh < 8; ++imh) {
          int im = imh >> 2, h = imh & 3;
          gb.g[kh * 8 + imh] = mkgb(Sh + (size_t)imh * 1048576 + kh * 512,
                                    qkvh + (size_t)(im * 3 + 2) * DSTR + h * 1024 + kh * 512,
                                    (kh ? oBh : oAh) + (size_t)im * 262144,
                                    nullptr, nullptr, nullptr,
                                    Mrw + imh * 1024, Inv + imh * 1024, h);
        }
      gemmh<64, 64, 2, 2, F_CD16 | F_CSCAT><<<dim3(1, 16, 16), TPB, 0, stream>>>(
          gb, 512, 1024, 4096, 256, 1.f, 0);
    }
    // K5: merge (adds the two K-half partials) -> msg fp32 (BM=32 -> 256 blocks)
    {
      GB16 gb{};
      for (int im = 0; im < 2; ++im)
        gb.g[im] = mkgb(merge_w + (size_t)i * 65536, oAh + (size_t)im * 262144,
                        msg + (size_t)im * DSTR, merge_b + (size_t)i * 256,
                        oBh + (size_t)im * 262144);
      gemmh<32, 64, 0, 2, F_BADD><<<dim3(16, 8, 2), TPB, 0, stream>>>(
          gb, 256, 256, 256, 1024, 1.f, 0);
    }
    // K6: mlp0 on concat([x, msg]) -> tbh f16
    {
      GB16 gb{};
      for (int im = 0; im < 2; ++im)
        gb.g[im] = mkgb(mlp_w0 + (size_t)i * 262144, xs[im],
                        tbh + (size_t)im * 524288, mlp_b0 + (size_t)i * 512,
                        msg + (size_t)im * DSTR);
      gemmh<64, 64, 0, 0, F_BCONCAT | F_CD16><<<dim3(16, 8, 2), TPB, 0, stream>>>(
          gb, 512, 512, 1024, 1024, 1.f, 256);
    }
    // K7: per-channel inorm stats
    rowstats2_h<<<256, TPB, 0, stream>>>(tbh, muA, rsA);
    // K8: mlp1 with fused inorm+relu on B, fp32 residual -> dn (BM=32)
    {
      GB16 gb{};
      for (int im = 0; im < 2; ++im)
        gb.g[im] = mkgb(mlp_w1 + (size_t)i * 131072, tbh + (size_t)im * 524288,
                        dn + (size_t)im * DSTR, mlp_b1 + (size_t)i * 256,
                        nullptr, xs[im],
                        muA + (size_t)im * 512, rsA + (size_t)im * 512);
      gemmh<32, 64, 0, 1, F_BNORM | F_RES><<<dim3(16, 8, 2), TPB, 0, stream>>>(
          gb, 512, 512, 1024, 1024, 1.f, 0);
    }
    float* tmp = dc; dc = dn; dn = tmp;
  }

  // ---- final projection -> mdbh f16 (BM=32) ----
  {
    GB16 gb{};
    for (int im = 0; im < 2; ++im)
      gb.g[im] = mkgb(final_w, dc + (size_t)im * DSTR, mdbh + (size_t)im * 262144,
                      final_b);
    gemmh<32, 64, 0, 0, F_CD16><<<dim3(16, 8, 2), TPB, 0, stream>>>(
        gb, 256, 256, 1024, 1024, 1.f, 0);
  }
  // ---- scores -> Zb fp32 + Zh/Zth f16 ----
  {
    GB16 gb{};
    gb.g[0] = mkgb(mdbh, mdbh + 262144, Zb, nullptr, nullptr, nullptr,
                   nullptr, nullptr, 0, Zh, Zth);
    gemmh<64, 64, 1, 1, F_OUT2><<<dim3(16, 16, 1), TPB, 0, stream>>>(
        gb, 256, 1024, 1024, ZLD, 0.0625f, 0);
  }
  fill_bins<<<5, TPB, 0, stream>>>(Zb, alpha_p, vF, bar);

  // ---- Sinkhorn: one persistent kernel, barrier + block-consolidated consume ----
  sink_persist<<<SINKB, TPB, 0, stream>>>(Zh, Zth, uF, vF, bar, alpha_p);

  // ---- output ----
  assemble<<<4105, TPB, 0, stream>>>(Zb, uF, vF, (float*)d_out);
}